// Round 1
// baseline (135.814 us; speedup 1.0000x reference)
//
#include <hip/hip_runtime.h>

#define HDIM 128
#define BDIM 32

// K1: pre-LN (over H=128) + down-projection d = h @ down_w^T + zero zbuf row.
__global__ __launch_bounds__(HDIM) void k1_preln_down(
    const float* __restrict__ x,
    const float* __restrict__ pre_g,
    const float* __restrict__ pre_b,
    const float* __restrict__ down_w,   // [BDIM, HDIM]
    float* __restrict__ h,              // [N, HDIM]
    float* __restrict__ d,              // [N, BDIM]
    float* __restrict__ zbuf) {         // [N, BDIM]
  const int n = blockIdx.x;
  const int t = threadIdx.x;            // 0..127
  __shared__ float lds_h[HDIM];
  __shared__ float red[4];

  float v = x[(size_t)n * HDIM + t];
  float s = v, s2 = v * v;
  #pragma unroll
  for (int o = 32; o > 0; o >>= 1) {
    s  += __shfl_down(s,  o, 64);
    s2 += __shfl_down(s2, o, 64);
  }
  const int wid = t >> 6;
  if ((t & 63) == 0) { red[wid * 2] = s; red[wid * 2 + 1] = s2; }
  __syncthreads();
  const float mean = (red[0] + red[2]) * (1.0f / HDIM);
  const float var  = (red[1] + red[3]) * (1.0f / HDIM) - mean * mean;
  const float rs   = rsqrtf(var + 1e-5f);
  const float hv   = (v - mean) * rs * pre_g[t] + pre_b[t];
  h[(size_t)n * HDIM + t] = hv;
  lds_h[t] = hv;
  __syncthreads();
  if (t < BDIM) {
    const float* wr = down_w + t * HDIM;
    float acc = 0.f;
    #pragma unroll 8
    for (int j = 0; j < HDIM; ++j) acc += lds_h[j] * wr[j];
    d[(size_t)n * BDIM + t]    = acc;
    zbuf[(size_t)n * BDIM + t] = 0.f;   // self-init (ws is poisoned 0xAA)
  }
}

// K2: edge scatter. One thread per (edge, k): zbuf[src,k] += d[dst,k].
__global__ __launch_bounds__(256) void k2_scatter(
    const int* __restrict__ ei,         // [2, E] (row0 = src, row1 = dst)
    int E,
    const float* __restrict__ d,        // [N, BDIM]
    float* __restrict__ zbuf) {         // [N, BDIM]
  const int tid = blockIdx.x * blockDim.x + threadIdx.x;
  const int e = tid >> 5;
  const int k = tid & 31;
  if (e >= E) return;
  const int src = ei[e];
  const int dst = ei[E + e];
  atomicAdd(&zbuf[(size_t)src * BDIM + k], d[(size_t)dst * BDIM + k]);
}

// K3: z = zbuf + down_b; u = z @ up_w^T + up_b; r = relu(u) + h; post-LN.
__global__ __launch_bounds__(HDIM) void k3_up_postln(
    const float* __restrict__ zbuf,     // [N, BDIM]
    const float* __restrict__ down_b,   // [BDIM]
    const float* __restrict__ up_w,     // [HDIM, BDIM]
    const float* __restrict__ up_b,     // [HDIM]
    const float* __restrict__ h,        // [N, HDIM]
    const float* __restrict__ post_g,
    const float* __restrict__ post_b,
    float* __restrict__ out) {          // [N, HDIM]
  const int n = blockIdx.x;
  const int t = threadIdx.x;            // 0..127
  __shared__ float z[BDIM];
  __shared__ float red[4];

  if (t < BDIM) z[t] = zbuf[(size_t)n * BDIM + t] + down_b[t];
  __syncthreads();

  const float* wr = up_w + t * BDIM;
  float acc = up_b[t];
  #pragma unroll
  for (int k = 0; k < BDIM; ++k) acc += z[k] * wr[k];

  const float r = fmaxf(acc, 0.f) + h[(size_t)n * HDIM + t];

  float s = r, s2 = r * r;
  #pragma unroll
  for (int o = 32; o > 0; o >>= 1) {
    s  += __shfl_down(s,  o, 64);
    s2 += __shfl_down(s2, o, 64);
  }
  const int wid = t >> 6;
  if ((t & 63) == 0) { red[wid * 2] = s; red[wid * 2 + 1] = s2; }
  __syncthreads();
  const float mean = (red[0] + red[2]) * (1.0f / HDIM);
  const float var  = (red[1] + red[3]) * (1.0f / HDIM) - mean * mean;
  const float rs   = rsqrtf(var + 1e-5f);
  out[(size_t)n * HDIM + t] = (r - mean) * rs * post_g[t] + post_b[t];
}

extern "C" void kernel_launch(void* const* d_in, const int* in_sizes, int n_in,
                              void* d_out, int out_size, void* d_ws, size_t ws_size,
                              hipStream_t stream) {
  const float* x      = (const float*)d_in[0];
  const int*   ei     = (const int*)  d_in[1];
  const float* down_w = (const float*)d_in[2];
  const float* down_b = (const float*)d_in[3];
  const float* up_w   = (const float*)d_in[4];
  const float* up_b   = (const float*)d_in[5];
  const float* pre_g  = (const float*)d_in[6];
  const float* pre_b  = (const float*)d_in[7];
  const float* post_g = (const float*)d_in[8];
  const float* post_b = (const float*)d_in[9];

  const int N = in_sizes[0] / HDIM;     // 16384
  const int E = in_sizes[1] / 2;        // 524288

  float* h    = (float*)d_ws;           // N*HDIM floats (8 MB)
  float* d    = h + (size_t)N * HDIM;   // N*BDIM floats (2 MB)
  float* zbuf = d + (size_t)N * BDIM;   // N*BDIM floats (2 MB)

  k1_preln_down<<<N, HDIM, 0, stream>>>(x, pre_g, pre_b, down_w, h, d, zbuf);

  const long long scatter_threads = (long long)E * BDIM;
  const int k2_blocks = (int)((scatter_threads + 255) / 256);
  k2_scatter<<<k2_blocks, 256, 0, stream>>>(ei, E, d, zbuf);

  k3_up_postln<<<N, HDIM, 0, stream>>>(zbuf, down_b, up_w, up_b, h,
                                       post_g, post_b, (float*)d_out);
}

// Round 2
// 134.222 us; speedup vs baseline: 1.0119x; 1.0119x over previous
//
#include <hip/hip_runtime.h>

#define H 128
#define B 32

// ---- K1: pre-LN + down-proj (d = h @ down_w^T) + zero count ----
// block=256, 8 nodes/block, half-wave (32 lanes) per node.
__global__ __launch_bounds__(256) void k1_preln_down(
    const float* __restrict__ x,
    const float* __restrict__ pre_g, const float* __restrict__ pre_b,
    const float* __restrict__ down_w,      // [B][H]
    float* __restrict__ h,                 // [N][H]
    float* __restrict__ dmat,              // [N][B]
    int* __restrict__ count) {             // [N]
  __shared__ float wt[H * 33];             // wt[j*33+k] = down_w[k][j]
  const int t = threadIdx.x;
  #pragma unroll
  for (int i = 0; i < 16; ++i) {
    int idx = i * 256 + t;                 // 4096 elems
    int k = idx >> 7, j = idx & 127;
    wt[j * 33 + k] = down_w[idx];
  }
  if (t < 8) count[blockIdx.x * 8 + t] = 0;  // self-init histogram slice
  __syncthreads();

  const int lane = t & 63;
  const int half = lane >> 5;
  const int l = lane & 31;
  const int n = blockIdx.x * 8 + (t >> 6) * 2 + half;

  float4 x4 = *(const float4*)(x + (size_t)n * H + 4 * l);
  float s  = x4.x + x4.y + x4.z + x4.w;
  float s2 = x4.x * x4.x + x4.y * x4.y + x4.z * x4.z + x4.w * x4.w;
  #pragma unroll
  for (int o = 16; o > 0; o >>= 1) {
    s  += __shfl_xor(s,  o, 32);
    s2 += __shfl_xor(s2, o, 32);
  }
  const float mean = s * (1.0f / H);
  const float var  = s2 * (1.0f / H) - mean * mean;
  const float rs   = rsqrtf(var + 1e-5f);
  float4 g4 = *(const float4*)(pre_g + 4 * l);
  float4 b4 = *(const float4*)(pre_b + 4 * l);
  float4 hv;
  hv.x = (x4.x - mean) * rs * g4.x + b4.x;
  hv.y = (x4.y - mean) * rs * g4.y + b4.y;
  hv.z = (x4.z - mean) * rs * g4.z + b4.z;
  hv.w = (x4.w - mean) * rs * g4.w + b4.w;
  *(float4*)(h + (size_t)n * H + 4 * l) = hv;

  float acc = 0.f;
  #pragma unroll
  for (int src = 0; src < 32; ++src) {
    float a0 = __shfl(hv.x, src, 32);
    float a1 = __shfl(hv.y, src, 32);
    float a2 = __shfl(hv.z, src, 32);
    float a3 = __shfl(hv.w, src, 32);
    const float* w = wt + (4 * src) * 33 + l;
    acc += a0 * w[0] + a1 * w[33] + a2 * w[66] + a3 * w[99];
  }
  dmat[(size_t)n * B + l] = acc;
}

// ---- K2a: histogram of src ----
__global__ __launch_bounds__(256) void k_hist(const int* __restrict__ ei, int E,
                                              int* __restrict__ count) {
  int e = blockIdx.x * 256 + threadIdx.x;
  if (e < E) atomicAdd(&count[ei[e]], 1);
}

// ---- K2b: exclusive scan (single block, 1024 threads) ----
__global__ __launch_bounds__(1024) void k_scan(const int* __restrict__ count,
                                               int* __restrict__ offs,
                                               int* __restrict__ cursor, int N) {
  const int t = threadIdx.x;
  const int PER = (N + 1023) / 1024;       // 16 for N=16384
  int loc[32];
  int run = 0;
  for (int i = 0; i < PER; ++i) {
    int idx = t * PER + i;
    loc[i] = run;
    run += (idx < N) ? count[idx] : 0;
  }
  __shared__ int ps[1024];
  ps[t] = run;
  __syncthreads();
  for (int off = 1; off < 1024; off <<= 1) {
    int v = (t >= off) ? ps[t - off] : 0;
    __syncthreads();
    ps[t] += v;
    __syncthreads();
  }
  int base = (t > 0) ? ps[t - 1] : 0;
  for (int i = 0; i < PER; ++i) {
    int idx = t * PER + i;
    if (idx < N) { int o = base + loc[i]; offs[idx] = o; cursor[idx] = o; }
  }
  if (t == 1023) offs[N] = ps[1023];
}

// ---- K2c: reorder edges into CSR (dst sorted by src) ----
__global__ __launch_bounds__(256) void k_reorder(const int* __restrict__ ei, int E,
                                                 int* __restrict__ cursor,
                                                 int* __restrict__ sdst) {
  int e = blockIdx.x * 256 + threadIdx.x;
  if (e < E) {
    int src = ei[e];
    int dst = ei[E + e];
    int pos = atomicAdd(&cursor[src], 1);
    sdst[pos] = dst;
  }
}

// ---- K2d: gather z[n] = sum_{e in CSR[n]} d[dst_e] + down_b ----
// one wave per node; halves split edges; lanes 0..31 = k.
__global__ __launch_bounds__(256) void k_gather(
    const int* __restrict__ offs, const int* __restrict__ sdst,
    const float* __restrict__ dmat, const float* __restrict__ down_b,
    float* __restrict__ zbuf, int N) {
  const int lane = threadIdx.x & 63;
  const int k = lane & 31, half = lane >> 5;
  const int n = blockIdx.x * 4 + (threadIdx.x >> 6);
  if (n >= N) return;
  const int beg = offs[n], end = offs[n + 1];
  float acc = 0.f;
  for (int i = beg + half; i < end; i += 2)
    acc += dmat[(size_t)sdst[i] * B + k];
  acc += __shfl_xor(acc, 32, 64);
  if (half == 0) zbuf[(size_t)n * B + k] = acc + down_b[k];
}

// ---- K3: up-proj + ReLU + residual + post-LN ----
// block=256, 16 nodes/block, wave per node (4 serial passes).
__global__ __launch_bounds__(256) void k3_up_postln(
    const float* __restrict__ zbuf,        // [N][B] (incl. down_b)
    const float* __restrict__ up_w,        // [H][B]
    const float* __restrict__ up_b,
    const float* __restrict__ hbuf,        // [N][H]
    const float* __restrict__ post_g, const float* __restrict__ post_b,
    float* __restrict__ out, int N) {
  __shared__ float uwt[B * 130];           // uwt[c*130+r] = up_w[r][c]
  const int t = threadIdx.x;
  #pragma unroll
  for (int i = 0; i < 16; ++i) {
    int idx = i * 256 + t;                 // 4096 elems
    int r = idx >> 5, c = idx & 31;
    uwt[c * 130 + r] = up_w[idx];
  }
  __syncthreads();
  const int lane = t & 63;
  const int wid = t >> 6;
  #pragma unroll
  for (int p = 0; p < 4; ++p) {
    const int n = blockIdx.x * 16 + wid * 4 + p;
    float zv = (lane < 32) ? zbuf[(size_t)n * B + lane] : 0.f;
    float2 h2 = *(const float2*)(hbuf + (size_t)n * H + 2 * lane);
    float2 ub = *(const float2*)(up_b + 2 * lane);
    float u0 = ub.x, u1 = ub.y;
    #pragma unroll
    for (int k = 0; k < 32; ++k) {
      float zk = __shfl(zv, k, 64);
      float2 w2 = *(const float2*)(uwt + k * 130 + 2 * lane);
      u0 += zk * w2.x;
      u1 += zk * w2.y;
    }
    float r0 = fmaxf(u0, 0.f) + h2.x;
    float r1 = fmaxf(u1, 0.f) + h2.y;
    float s = r0 + r1, s2 = r0 * r0 + r1 * r1;
    #pragma unroll
    for (int o = 32; o > 0; o >>= 1) {
      s  += __shfl_xor(s,  o, 64);
      s2 += __shfl_xor(s2, o, 64);
    }
    const float mean = s * (1.0f / H);
    const float var  = s2 * (1.0f / H) - mean * mean;
    const float rsv  = rsqrtf(var + 1e-5f);
    float2 pg = *(const float2*)(post_g + 2 * lane);
    float2 pb = *(const float2*)(post_b + 2 * lane);
    float2 o2;
    o2.x = (r0 - mean) * rsv * pg.x + pb.x;
    o2.y = (r1 - mean) * rsv * pg.y + pb.y;
    *(float2*)(out + (size_t)n * H + 2 * lane) = o2;
  }
}

extern "C" void kernel_launch(void* const* d_in, const int* in_sizes, int n_in,
                              void* d_out, int out_size, void* d_ws, size_t ws_size,
                              hipStream_t stream) {
  const float* x      = (const float*)d_in[0];
  const int*   ei     = (const int*)  d_in[1];
  const float* down_w = (const float*)d_in[2];
  const float* down_b = (const float*)d_in[3];
  const float* up_w   = (const float*)d_in[4];
  const float* up_b   = (const float*)d_in[5];
  const float* pre_g  = (const float*)d_in[6];
  const float* pre_b  = (const float*)d_in[7];
  const float* post_g = (const float*)d_in[8];
  const float* post_b = (const float*)d_in[9];

  const int N = in_sizes[0] / H;          // 16384
  const int E = in_sizes[1] / 2;          // 524288

  float* hbuf = (float*)d_ws;             // N*H
  float* dmat = hbuf + (size_t)N * H;     // N*B
  float* zbuf = dmat + (size_t)N * B;     // N*B
  int* sdst   = (int*)(zbuf + (size_t)N * B);  // E
  int* count  = sdst + E;                 // N
  int* offs   = count + N;                // N+1
  int* cursor = offs + N + 1;             // N

  k1_preln_down<<<N / 8, 256, 0, stream>>>(x, pre_g, pre_b, down_w, hbuf, dmat, count);
  k_hist<<<(E + 255) / 256, 256, 0, stream>>>(ei, E, count);
  k_scan<<<1, 1024, 0, stream>>>(count, offs, cursor, N);
  k_reorder<<<(E + 255) / 256, 256, 0, stream>>>(ei, E, cursor, sdst);
  k_gather<<<(N + 3) / 4, 256, 0, stream>>>(offs, sdst, dmat, down_b, zbuf, N);
  k3_up_postln<<<N / 16, 256, 0, stream>>>(zbuf, up_w, up_b, hbuf, post_g, post_b,
                                           (float*)d_out, N);
}

// Round 3
// 120.016 us; speedup vs baseline: 1.1316x; 1.1184x over previous
//
#include <hip/hip_runtime.h>

#define H 128
#define B 32

// ---- K1: pre-LN + down-proj (d = h @ down_w^T) + zero count ----
// block=256, 8 nodes/block, half-wave (32 lanes) per node.
__global__ __launch_bounds__(256) void k1_preln_down(
    const float* __restrict__ x,
    const float* __restrict__ pre_g, const float* __restrict__ pre_b,
    const float* __restrict__ down_w,      // [B][H]
    float* __restrict__ h,                 // [N][H]
    float* __restrict__ dmat,              // [N][B]
    int* __restrict__ count) {             // [N]
  __shared__ float wt[H * 33];             // wt[j*33+k] = down_w[k][j]
  const int t = threadIdx.x;
  #pragma unroll
  for (int i = 0; i < 16; ++i) {
    int idx = i * 256 + t;                 // 4096 elems
    int k = idx >> 7, j = idx & 127;
    wt[j * 33 + k] = down_w[idx];
  }
  if (t < 8) count[blockIdx.x * 8 + t] = 0;  // self-init histogram slice
  __syncthreads();

  const int lane = t & 63;
  const int half = lane >> 5;
  const int l = lane & 31;
  const int n = blockIdx.x * 8 + (t >> 6) * 2 + half;

  float4 x4 = *(const float4*)(x + (size_t)n * H + 4 * l);
  float s  = x4.x + x4.y + x4.z + x4.w;
  float s2 = x4.x * x4.x + x4.y * x4.y + x4.z * x4.z + x4.w * x4.w;
  #pragma unroll
  for (int o = 16; o > 0; o >>= 1) {
    s  += __shfl_xor(s,  o, 32);
    s2 += __shfl_xor(s2, o, 32);
  }
  const float mean = s * (1.0f / H);
  const float var  = s2 * (1.0f / H) - mean * mean;
  const float rs   = rsqrtf(var + 1e-5f);
  float4 g4 = *(const float4*)(pre_g + 4 * l);
  float4 b4 = *(const float4*)(pre_b + 4 * l);
  float4 hv;
  hv.x = (x4.x - mean) * rs * g4.x + b4.x;
  hv.y = (x4.y - mean) * rs * g4.y + b4.y;
  hv.z = (x4.z - mean) * rs * g4.z + b4.z;
  hv.w = (x4.w - mean) * rs * g4.w + b4.w;
  *(float4*)(h + (size_t)n * H + 4 * l) = hv;

  float acc = 0.f;
  #pragma unroll
  for (int src = 0; src < 32; ++src) {
    float a0 = __shfl(hv.x, src, 32);
    float a1 = __shfl(hv.y, src, 32);
    float a2 = __shfl(hv.z, src, 32);
    float a3 = __shfl(hv.w, src, 32);
    const float* w = wt + (4 * src) * 33 + l;
    acc += a0 * w[0] + a1 * w[33] + a2 * w[66] + a3 * w[99];
  }
  dmat[(size_t)n * B + l] = acc;
}

// ---- K2a: histogram of src ----
__global__ __launch_bounds__(256) void k_hist(const int* __restrict__ ei, int E,
                                              int* __restrict__ count) {
  int e = blockIdx.x * 256 + threadIdx.x;
  if (e < E) atomicAdd(&count[ei[e]], 1);
}

// ---- K2b: exclusive scan (single block, 1024 threads, 16/thread in regs) ----
__global__ __launch_bounds__(1024) void k_scan(const int* __restrict__ count,
                                               int* __restrict__ offs,
                                               int* __restrict__ cursor, int N) {
  const int t = threadIdx.x;
  int v[16];                              // static-indexed -> registers
  #pragma unroll
  for (int i = 0; i < 16; ++i) {
    int idx = t * 16 + i;
    v[i] = (idx < N) ? count[idx] : 0;
  }
  int run = 0;
  #pragma unroll
  for (int i = 0; i < 16; ++i) { int tmp = v[i]; v[i] = run; run += tmp; }
  __shared__ int ps[1024];
  ps[t] = run;
  __syncthreads();
  #pragma unroll
  for (int off = 1; off < 1024; off <<= 1) {
    int p = (t >= off) ? ps[t - off] : 0;
    __syncthreads();
    ps[t] += p;
    __syncthreads();
  }
  const int base = (t > 0) ? ps[t - 1] : 0;
  #pragma unroll
  for (int i = 0; i < 16; ++i) {
    int idx = t * 16 + i;
    if (idx < N) { int o = base + v[i]; offs[idx] = o; cursor[idx] = o; }
  }
  if (t == 1023) offs[N] = ps[1023];
}

// ---- K2c: reorder edges into CSR (dst sorted by src) ----
__global__ __launch_bounds__(256) void k_reorder(const int* __restrict__ ei, int E,
                                                 int* __restrict__ cursor,
                                                 int* __restrict__ sdst) {
  int e = blockIdx.x * 256 + threadIdx.x;
  if (e < E) {
    int src = ei[e];
    int dst = ei[E + e];
    int pos = atomicAdd(&cursor[src], 1);
    sdst[pos] = dst;
  }
}

// ---- K3 fused: CSR gather + down_b + up-proj + ReLU + residual + post-LN ----
// block=256 = 4 waves; one wave per node.
__global__ __launch_bounds__(256) void k3_fused(
    const int* __restrict__ offs, const int* __restrict__ sdst,
    const float* __restrict__ dmat,        // [N][B]
    const float* __restrict__ down_b,      // [B]
    const float* __restrict__ up_w,        // [H][B]
    const float* __restrict__ up_b,        // [H]
    const float* __restrict__ hbuf,        // [N][H]
    const float* __restrict__ post_g, const float* __restrict__ post_b,
    float* __restrict__ out, int N) {
  __shared__ float uwt[B * 130];           // uwt[c*130+r] = up_w[r][c]
  const int t = threadIdx.x;
  #pragma unroll
  for (int i = 0; i < 16; ++i) {
    int idx = i * 256 + t;                 // 4096 elems
    int r = idx >> 5, c = idx & 31;
    uwt[c * 130 + r] = up_w[idx];
  }
  __syncthreads();

  const int lane = t & 63;
  const int k = lane & 31, half = lane >> 5;
  const int n = blockIdx.x * 4 + (t >> 6);
  if (n >= N) return;

  // gather: z[k] = sum_{e in CSR[n]} dmat[dst_e][k]  (halves split edges)
  const int beg = offs[n], end = offs[n + 1];
  float acc = 0.f;
  int i = beg + half;
  for (; i + 4 <= end; i += 4) {           // 2-deep to break dep chain
    int d0 = sdst[i], d1 = sdst[i + 2];
    float v0 = dmat[(size_t)d0 * B + k];
    float v1 = dmat[(size_t)d1 * B + k];
    acc += v0 + v1;
  }
  for (; i < end; i += 2) acc += dmat[(size_t)sdst[i] * B + k];
  acc += __shfl_xor(acc, 32, 64);          // both halves now hold full z[k]
  const float zv = acc + down_b[k];

  // up-proj: each lane computes outputs r = 2*lane, 2*lane+1
  float2 h2 = *(const float2*)(hbuf + (size_t)n * H + 2 * lane);
  float2 ub = *(const float2*)(up_b + 2 * lane);
  float u0 = ub.x, u1 = ub.y;
  #pragma unroll
  for (int kk = 0; kk < 32; ++kk) {
    float zk = __shfl(zv, kk, 64);
    float2 w2 = *(const float2*)(uwt + kk * 130 + 2 * lane);
    u0 += zk * w2.x;
    u1 += zk * w2.y;
  }
  float r0 = fmaxf(u0, 0.f) + h2.x;
  float r1 = fmaxf(u1, 0.f) + h2.y;

  // post-LN over H=128 (2 vals x 64 lanes)
  float s = r0 + r1, s2 = r0 * r0 + r1 * r1;
  #pragma unroll
  for (int o = 32; o > 0; o >>= 1) {
    s  += __shfl_xor(s,  o, 64);
    s2 += __shfl_xor(s2, o, 64);
  }
  const float mean = s * (1.0f / H);
  const float var  = s2 * (1.0f / H) - mean * mean;
  const float rsv  = rsqrtf(var + 1e-5f);
  float2 pg = *(const float2*)(post_g + 2 * lane);
  float2 pb = *(const float2*)(post_b + 2 * lane);
  float2 o2;
  o2.x = (r0 - mean) * rsv * pg.x + pb.x;
  o2.y = (r1 - mean) * rsv * pg.y + pb.y;
  *(float2*)(out + (size_t)n * H + 2 * lane) = o2;
}

extern "C" void kernel_launch(void* const* d_in, const int* in_sizes, int n_in,
                              void* d_out, int out_size, void* d_ws, size_t ws_size,
                              hipStream_t stream) {
  const float* x      = (const float*)d_in[0];
  const int*   ei     = (const int*)  d_in[1];
  const float* down_w = (const float*)d_in[2];
  const float* down_b = (const float*)d_in[3];
  const float* up_w   = (const float*)d_in[4];
  const float* up_b   = (const float*)d_in[5];
  const float* pre_g  = (const float*)d_in[6];
  const float* pre_b  = (const float*)d_in[7];
  const float* post_g = (const float*)d_in[8];
  const float* post_b = (const float*)d_in[9];

  const int N = in_sizes[0] / H;          // 16384
  const int E = in_sizes[1] / 2;          // 524288

  float* hbuf = (float*)d_ws;             // N*H
  float* dmat = hbuf + (size_t)N * H;     // N*B
  int* sdst   = (int*)(dmat + (size_t)N * B);  // E
  int* count  = sdst + E;                 // N
  int* offs   = count + N;                // N+1
  int* cursor = offs + N + 1;             // N

  k1_preln_down<<<N / 8, 256, 0, stream>>>(x, pre_g, pre_b, down_w, hbuf, dmat, count);
  k_hist<<<(E + 255) / 256, 256, 0, stream>>>(ei, E, count);
  k_scan<<<1, 1024, 0, stream>>>(count, offs, cursor, N);
  k_reorder<<<(E + 255) / 256, 256, 0, stream>>>(ei, E, cursor, sdst);
  k3_fused<<<(N + 3) / 4, 256, 0, stream>>>(offs, sdst, dmat, down_b, up_w, up_b,
                                            hbuf, post_g, post_b, (float*)d_out, N);
}